// Round 23
// baseline (104.444 us; speedup 1.0000x reference)
//
#include <hip/hip_runtime.h>
#include <math.h>

#define N_SEQ 1024
#define LL 64
#define DH 256
#define DX 128
#define MQ 8192
#define GG 4096
#define NTYP 64
#define NMEM 262144

typedef __attribute__((ext_vector_type(8))) short short8v;
typedef __attribute__((ext_vector_type(4))) float float4v;

__device__ __forceinline__ unsigned short f2bf(float x) {
    unsigned int u = __float_as_uint(x);
    u += 0x7FFFu + ((u >> 16) & 1u);   // round-to-nearest-even
    return (unsigned short)(u >> 16);
}

// ---------------- init: Wq->bf16 (0..127), zero cnt (128..131),
//                  per-n ranges (132..135) ----------------------------------
__global__ __launch_bounds__(256) void k_init(const float* __restrict__ Wq,
                                              unsigned short* __restrict__ WqB,
                                              int4* __restrict__ cnt4,
                                              const int* __restrict__ idx,
                                              int* __restrict__ ofs_n) {
    int b = blockIdx.x, tid = threadIdx.x;
    if (b < 128) {
        int i = (b * 256 + tid) * 4;
        float4 v = *(const float4*)(Wq + i);
        ushort4 o;
        o.x = f2bf(v.x); o.y = f2bf(v.y); o.z = f2bf(v.z); o.w = f2bf(v.w);
        *(ushort4*)(WqB + i) = o;
    } else if (b < 132) {
        cnt4[(b - 128) * 256 + tid] = (int4){0, 0, 0, 0};
    } else {
        int n = (b - 132) * 256 + tid;
        int lo = 0, hi = MQ;
        while (lo < hi) {
            int mid = (lo + hi) >> 1;
            if (idx[mid] < n) lo = mid + 1; else hi = mid;
        }
        ofs_n[n] = lo;
        if (n == 0) ofs_n[N_SEQ] = MQ;
    }
}

// ---------------- hist (blocks 0..1023) || BT build (blocks 1024..1043) -----
__global__ __launch_bounds__(256) void k_histw(const int* __restrict__ grp,
                                               int* __restrict__ cnt,
                                               int* __restrict__ rank,
                                               const float* __restrict__ Wk,
                                               const float* __restrict__ bq,
                                               const unsigned short* __restrict__ WqB,
                                               const float* __restrict__ Wrel,
                                               const float* __restrict__ brel,
                                               unsigned short* __restrict__ BT,
                                               float* __restrict__ bias) {
    __shared__ __align__(16) unsigned short A[16 * 256];
    __shared__ float bred[16][17];
    int b = blockIdx.x, tid = threadIdx.x;
    if (b < 1024) {
        int i = b * 256 + tid;
        rank[i] = atomicAdd(&cnt[grp[i]], 1);
        return;
    }
    int b2 = b - 1024;
    if (b2 < 16) {
        int n0 = b2 * 16;
        {
            int r = tid >> 4;
            int kc = (tid & 15) * 16;
            const float4* s4 = (const float4*)(Wk + (size_t)(n0 + r) * 256 + kc);
            unsigned short* Arow = A + r * 256;
#pragma unroll
            for (int j = 0; j < 2; ++j) {
                float4 lo = s4[j * 2], hi = s4[j * 2 + 1];
                unsigned short tmp[8];
                tmp[0] = f2bf(lo.x); tmp[1] = f2bf(lo.y);
                tmp[2] = f2bf(lo.z); tmp[3] = f2bf(lo.w);
                tmp[4] = f2bf(hi.x); tmp[5] = f2bf(hi.y);
                tmp[6] = f2bf(hi.z); tmp[7] = f2bf(hi.w);
                int c = (kc >> 3) + j;
                int cs = (c & ~7) | ((c & 7) ^ (r & 7));
                *(int4*)(Arow + cs * 8) = *(int4*)tmp;
            }
        }
        __syncthreads();
        int w = tid >> 6, lane = tid & 63;
        int r = lane & 15, kq = lane >> 4;
        float4v acc[8];
#pragma unroll
        for (int t = 0; t < 8; ++t) acc[t] = (float4v){0.f, 0.f, 0.f, 0.f};
        const unsigned short* Arow = A + r * 256;
#pragma unroll
        for (int ks = 0; ks < 8; ++ks) {
            int c = ks * 4 + kq;
            int cs = (c & ~7) | ((c & 7) ^ (r & 7));
            short8v a = *(const short8v*)(Arow + cs * 8);
            int kk = ks * 32 + kq * 8;
#pragma unroll
            for (int t = 0; t < 8; ++t) {
                int jcol = w * 128 + t * 16 + r;
                short8v bf = *(const short8v*)(WqB + (size_t)jcol * 256 + kk);
                acc[t] = __builtin_amdgcn_mfma_f32_16x16x32_bf16(a, bf, acc[t], 0, 0, 0);
            }
        }
#pragma unroll
        for (int t = 0; t < 8; ++t) {
            int jcol = w * 128 + t * 16 + r;
#pragma unroll
            for (int j = 0; j < 4; ++j)
                BT[(size_t)(n0 + kq * 4 + j) * 512 + jcol] = f2bf(acc[t][j]);
        }
        {
            int n16 = tid >> 4, seg = tid & 15;
            const float* wkr = Wk + (size_t)(n0 + n16) * 256 + seg * 16;
            const float* bqr = bq + seg * 16;
            float pb = 0.f;
#pragma unroll
            for (int i = 0; i < 16; ++i) pb += wkr[i] * bqr[i];
            bred[n16][seg] = pb;
        }
        __syncthreads();
        if (tid < 16) {
            float s = 0.f;
#pragma unroll
            for (int k2 = 0; k2 < 16; ++k2) s += bred[tid][k2];
            bias[n0 + tid] = s;
        }
    } else {
        int t0 = (b2 - 16) * 16;
#pragma unroll
        for (int jj = 0; jj < 2; ++jj) {
            int j = tid + jj * 256;
            const float* wr = Wrel + (size_t)j * NTYP + t0;
#pragma unroll
            for (int tt = 0; tt < 16; ++tt)
                BT[(size_t)(256 + t0 + tt) * 512 + j] = f2bf(wr[tt]);
        }
        if (b2 == 16 && tid < 64) bias[256 + tid] = brel[tid];
    }
}

// ---------------- scan (block 0, 256 thr) || gemm (blocks 1..512) -----------
__global__ __launch_bounds__(256) void k_sg(const int* __restrict__ cnt,
                                            int* __restrict__ ofs,
                                            const float* __restrict__ h_grp,
                                            const int* __restrict__ idx,
                                            const int* __restrict__ srcv,
                                            const int* __restrict__ dstv,
                                            const unsigned short* __restrict__ BT,
                                            const float* __restrict__ bias,
                                            unsigned short* __restrict__ qkb,
                                            float* __restrict__ part) {
    __shared__ __align__(16) unsigned short A[16 * 512];
    __shared__ int ns[16], ss[16], dsv[16];
    int b = blockIdx.x, tid = threadIdx.x;
    if (b == 0) {
        int* wsum = (int*)A;
        int lane = tid & 63, w = tid >> 6;
        int c[16];
        int tsum = 0;
        int base0 = tid * 16;
#pragma unroll
        for (int j = 0; j < 16; ++j) { c[j] = cnt[base0 + j]; tsum += c[j]; }
        int v = tsum;
        for (int o2 = 1; o2 < 64; o2 <<= 1) {
            int t = __shfl_up(v, o2);
            if (lane >= o2) v += t;
        }
        if (lane == 63) wsum[w] = v;
        __syncthreads();
        int wb = 0;
#pragma unroll
        for (int q2 = 0; q2 < 4; ++q2) if (q2 < w) wb += wsum[q2];
        int base = wb + v - tsum;
#pragma unroll
        for (int j = 0; j < 16; ++j) { ofs[base0 + j] = base; base += c[j]; }
        return;
    }
    int bid = b - 1;
    int swz = (bid & 7) * 64 + (bid >> 3);   // 512 blocks, XCD-chunked
    int m0 = swz * 16;
    if (tid < 16) {
        int m = m0 + tid;
        ns[tid] = idx[m];
        ss[tid] = srcv[m];
        dsv[tid] = dstv[m];
    }
    __syncthreads();
    {
        int r = tid >> 4;
        int kc = (tid & 15) * 32;
        const float* src = h_grp +
            ((size_t)ns[r] * LL + (kc < 256 ? ss[r] : dsv[r])) * DH + (kc & 255);
        const float4* s4 = (const float4*)src;
        float4 f[8];
#pragma unroll
        for (int j = 0; j < 8; ++j) f[j] = s4[j];
        unsigned short* Arow = A + r * 512;
#pragma unroll
        for (int j = 0; j < 4; ++j) {
            int c = (kc >> 3) + j;
            int cs = (c & ~7) | ((c & 7) ^ (r & 7));
            unsigned short tmp[8];
            float4 lo = f[j * 2], hi = f[j * 2 + 1];
            tmp[0] = f2bf(lo.x); tmp[1] = f2bf(lo.y);
            tmp[2] = f2bf(lo.z); tmp[3] = f2bf(lo.w);
            tmp[4] = f2bf(hi.x); tmp[5] = f2bf(hi.y);
            tmp[6] = f2bf(hi.z); tmp[7] = f2bf(hi.w);
            *(int4*)(Arow + cs * 8) = *(int4*)tmp;
        }
    }
    __syncthreads();

    int w = tid >> 6, lane = tid & 63;
    int r = lane & 15;
    int q = lane >> 4;
    int n0 = w * 80;
    float4v acc[5];
#pragma unroll
    for (int t = 0; t < 5; ++t) {
        float b3 = bias[n0 + t * 16 + r];
        acc[t] = (float4v){b3, b3, b3, b3};
    }
    const unsigned short* Arow = A + r * 512;
#pragma unroll 2
    for (int ks = 0; ks < 16; ++ks) {
        int c = ks * 4 + q;
        int cs = (c & ~7) | ((c & 7) ^ (r & 7));
        short8v a = *(const short8v*)(Arow + cs * 8);
        int kk = ks * 32 + q * 8;
#pragma unroll
        for (int t = 0; t < 5; ++t) {
            int n = n0 + t * 16 + r;
            short8v b3 = *(const short8v*)(BT + (size_t)n * 512 + kk);
            acc[t] = __builtin_amdgcn_mfma_f32_16x16x32_bf16(a, b3, acc[t], 0, 0, 0);
        }
    }
#pragma unroll
    for (int t = 0; t < 5; ++t) {
        int n = n0 + t * 16 + r;
        if (n < 256) {
#pragma unroll
            for (int j = 0; j < 4; ++j)
                qkb[(size_t)(m0 + q * 4 + j) * 256 + n] = f2bf(acc[t][j]);
        } else {
#pragma unroll
            for (int j = 0; j < 4; ++j)
                part[(size_t)(m0 + q * 4 + j) * NTYP + (n - 256)] = acc[t][j];
        }
    }
}

// ---------------- permute (blocks 0..1023) || score (blocks 1024..2047) -----
// score = attn9's GEMM2 + softmax, P -> global Pg[m][l] bf16 (no zw needed)
__global__ __launch_bounds__(256) void k_pscore(const int* __restrict__ grp,
                                                const int* __restrict__ mem,
                                                const int* __restrict__ ofs,
                                                const int* __restrict__ rank,
                                                int* __restrict__ tok_sorted,
                                                const float* __restrict__ h_grp,
                                                const int* __restrict__ ofs_n,
                                                const int* __restrict__ msk,
                                                const unsigned short* __restrict__ qkb,
                                                unsigned short* __restrict__ Pg) {
    __shared__ float red0[4][16], red1[4][16];
    int b = blockIdx.x, tid = threadIdx.x;
    if (b < 1024) {
        // ---- permute body (byte-identical) ----
        int i = b * 256 + tid;
        tok_sorted[ofs[grp[i]] + rank[i]] = mem[i];
        return;
    }
    // ---- score body (attn9 minus zwT/ctx) ----
    int bid = b - 1024;
    int n = (bid & 7) * 128 + (bid >> 3);      // XCD-chunked over 1024
    int start = ofs_n[n];
    int nq = ofs_n[n + 1] - start;
    if (nq <= 0) return;

    int w = tid >> 6, lane = tid & 63;
    int q15 = lane & 15, kq = lane >> 4;
    int mk = msk[n * LL + lane];

    // A-fragments direct from global h (loop-invariant): row 16w+q15
    const float* hrow = h_grp + ((size_t)n * LL + 16 * w + q15) * DH;
    short8v afrag[8];
#pragma unroll
    for (int ks = 0; ks < 8; ++ks) {
        const float4* p = (const float4*)(hrow + ks * 32 + kq * 8);
        float4 f0 = p[0], f1 = p[1];
        unsigned short t[8];
        t[0] = f2bf(f0.x); t[1] = f2bf(f0.y);
        t[2] = f2bf(f0.z); t[3] = f2bf(f0.w);
        t[4] = f2bf(f1.x); t[5] = f2bf(f1.y);
        t[6] = f2bf(f1.z); t[7] = f2bf(f1.w);
        afrag[ks] = *(short8v*)t;
    }

    for (int t0 = 0; t0 < nq; t0 += 16) {
        int nqt = nq - t0; if (nqt > 16) nqt = 16;
        int mq = start + t0 + (q15 < nqt ? q15 : 0);
        const unsigned short* qrow = qkb + (size_t)mq * 256;
        float4v sacc = (float4v){0.f, 0.f, 0.f, 0.f};
#pragma unroll
        for (int ks = 0; ks < 8; ++ks) {
            short8v b3 = *(const short8v*)(qrow + ks * 32 + kq * 8);
            sacc = __builtin_amdgcn_mfma_f32_16x16x32_bf16(afrag[ks], b3, sacc, 0, 0, 0);
        }
        float sv[4];
#pragma unroll
        for (int j = 0; j < 4; ++j) {
            int l = 16 * w + kq * 4 + j;
            int mkl = __shfl(mk, l);
            sv[j] = mkl ? sacc[j] * 0.0625f : -INFINITY;
        }
        float pmax = fmaxf(fmaxf(sv[0], sv[1]), fmaxf(sv[2], sv[3]));
        pmax = fmaxf(pmax, __shfl_xor(pmax, 16));
        pmax = fmaxf(pmax, __shfl_xor(pmax, 32));
        if (lane < 16) red0[w][lane] = pmax;
        __syncthreads();
        float mx = fmaxf(fmaxf(red0[0][q15], red0[1][q15]),
                         fmaxf(red0[2][q15], red0[3][q15]));
        float pe[4];
        float psum = 0.f;
#pragma unroll
        for (int j = 0; j < 4; ++j) { pe[j] = __expf(sv[j] - mx); psum += pe[j]; }
        psum += __shfl_xor(psum, 16);
        psum += __shfl_xor(psum, 32);
        if (lane < 16) red1[w][lane] = psum;
        __syncthreads();
        float inv = 1.0f / (red1[0][q15] + red1[1][q15] + red1[2][q15] + red1[3][q15]);
        ushort4 pk;
        pk.x = f2bf(pe[0] * inv); pk.y = f2bf(pe[1] * inv);
        pk.z = f2bf(pe[2] * inv); pk.w = f2bf(pe[3] * inv);
        if (q15 < nqt)
            *(ushort4*)(Pg + (size_t)(start + t0 + q15) * NTYP + 16 * w + kq * 4) = pk;
    }
}

// z[g] = sum tok_emb rows (float4 gather, 4 tokens in parallel);
// fused: zw[g] = z[g] @ Wrel[512:640]   (round-14/17 proven body)
__global__ __launch_bounds__(128) void k_zsum(const int* __restrict__ ofs,
                                              const int* __restrict__ cnt,
                                              const int* __restrict__ tok_sorted,
                                              const float* __restrict__ tok_emb,
                                              const float* __restrict__ Wrel,
                                              float* __restrict__ zw) {
    __shared__ int idxs[128];
    __shared__ float red[4][128];
    __shared__ float zs[128];
    int g = blockIdx.x;
    int tid = threadIdx.x;
    int gq = tid >> 5;
    int s = tid & 31;
    int start = ofs[g], n = cnt[g];
    float4 a0 = {0.f, 0.f, 0.f, 0.f}, a1 = {0.f, 0.f, 0.f, 0.f};
    for (int j0 = 0; j0 < n; j0 += 128) {
        __syncthreads();
        int rem = n - j0;
        if (tid < rem) idxs[tid] = tok_sorted[start + j0 + tid];
        __syncthreads();
        int kmax = rem < 128 ? rem : 128;
        int k = gq;
        for (; k + 4 < kmax; k += 8) {
            const float4* r0 = (const float4*)(tok_emb + (size_t)idxs[k] * DX);
            const float4* r1 = (const float4*)(tok_emb + (size_t)idxs[k + 4] * DX);
            float4 v0 = r0[s], v1 = r1[s];
            a0.x += v0.x; a0.y += v0.y; a0.z += v0.z; a0.w += v0.w;
            a1.x += v1.x; a1.y += v1.y; a1.z += v1.z; a1.w += v1.w;
        }
        if (k < kmax) {
            const float4* r0 = (const float4*)(tok_emb + (size_t)idxs[k] * DX);
            float4 v0 = r0[s];
            a0.x += v0.x; a0.y += v0.y; a0.z += v0.z; a0.w += v0.w;
        }
    }
    a0.x += a1.x; a0.y += a1.y; a0.z += a1.z; a0.w += a1.w;
    ((float4*)red[gq])[s] = a0;
    __syncthreads();
    zs[tid] = red[0][tid] + red[1][tid] + red[2][tid] + red[3][tid];
    __syncthreads();
    if (tid < NTYP) {
        float a2s = 0.f;
#pragma unroll 8
        for (int v = 0; v < DX; ++v)
            a2s += zs[v] * Wrel[(size_t)(512 + v) * NTYP + tid];
        zw[(size_t)g * NTYP + tid] = a2s;
    }
}

// ---------------- ctx: per-n, P from global, ctx MFMA + epilogue ------------
__global__ __launch_bounds__(256) void k_ctx(const int* __restrict__ ofs_n,
                                             const int* __restrict__ pos2grp,
                                             const float* __restrict__ zw,
                                             const unsigned short* __restrict__ Pg,
                                             const float* __restrict__ part,
                                             float* __restrict__ out) {
    __shared__ __align__(16) unsigned short zwT[64][72];   // 9.2 KB
    int bid = blockIdx.x;
    int n = (bid & 7) * 128 + (bid >> 3);      // XCD-chunked over 1024
    int start = ofs_n[n];
    int nq = ofs_n[n + 1] - start;
    if (nq <= 0) return;

    int tid = threadIdx.x;
    int w = tid >> 6, lane = tid & 63;
    int q15 = lane & 15, kq = lane >> 4;

    int gv = pos2grp[n * LL + lane];

    // stage zwT[c][l] = bf16(zw[g_l][c])
    {
        int l = 16 * w + (lane >> 2);
        int cb = (lane & 3) * 16;
        int gl = __shfl(gv, l);
        const float4* zr4 = (const float4*)(zw + (size_t)gl * NTYP + cb);
#pragma unroll
        for (int i4 = 0; i4 < 4; ++i4) {
            float4 zv = zr4[i4];
            zwT[cb + i4 * 4 + 0][l] = f2bf(zv.x);
            zwT[cb + i4 * 4 + 1][l] = f2bf(zv.y);
            zwT[cb + i4 * 4 + 2][l] = f2bf(zv.z);
            zwT[cb + i4 * 4 + 3][l] = f2bf(zv.w);
        }
    }
    __syncthreads();

    for (int t0 = 0; t0 < nq; t0 += 16) {
        int nqt = nq - t0; if (nqt > 16) nqt = 16;
        int mq = start + t0 + (q15 < nqt ? q15 : 0);
        float4v cacc[4];
#pragma unroll
        for (int ct = 0; ct < 4; ++ct) cacc[ct] = (float4v){0.f, 0.f, 0.f, 0.f};
#pragma unroll
        for (int ks = 0; ks < 2; ++ks) {
            short8v a = *(const short8v*)(Pg + (size_t)mq * NTYP + ks * 32 + kq * 8);
#pragma unroll
            for (int ct = 0; ct < 4; ++ct) {
                short8v b = *(const short8v*)(&zwT[ct * 16 + q15][ks * 32 + kq * 8]);
                cacc[ct] = __builtin_amdgcn_mfma_f32_16x16x32_bf16(a, b, cacc[ct], 0, 0, 0);
            }
        }
#pragma unroll
        for (int ct = 0; ct < 4; ++ct) {
            int col = ct * 16 + q15;
#pragma unroll
            for (int j = 0; j < 4; ++j) {
                int qrow2 = kq * 4 + j;
                if (qrow2 < nqt) {
                    size_t m = (size_t)(start + t0 + qrow2);
                    out[m * NTYP + col] = part[m * NTYP + col] + cacc[ct][j];
                }
            }
        }
    }
}

extern "C" void kernel_launch(void* const* d_in, const int* in_sizes, int n_in,
                              void* d_out, int out_size, void* d_ws, size_t ws_size,
                              hipStream_t stream) {
    const int*   mem     = (const int*)d_in[0];
    const int*   grp     = (const int*)d_in[1];
    const int*   pos2grp = (const int*)d_in[2];
    const float* h_grp   = (const float*)d_in[3];
    const int*   msk     = (const int*)d_in[4];
    const int*   idx     = (const int*)d_in[5];
    const int*   srcv    = (const int*)d_in[6];
    const int*   dstv    = (const int*)d_in[7];
    // d_in[8] = typ (unused by the reference)
    const float* tok_emb = (const float*)d_in[9];
    const float* Wq      = (const float*)d_in[10];
    const float* bq      = (const float*)d_in[11];
    const float* Wk      = (const float*)d_in[12];
    const float* bk      = (const float*)d_in[13];  // softmax-invariant: unused
    const float* Wrel    = (const float*)d_in[14];
    const float* brel    = (const float*)d_in[15];
    float* out = (float*)d_out;
    (void)bk;

    float* ws = (float*)d_ws;
    size_t off = 0;
    float* zw   = ws + off; off += (size_t)GG * NTYP;       // 262144
    unsigned short* qkb = (unsigned short*)(ws + off); off += (size_t)MQ * 256 / 2;
    float* part = ws + off; off += (size_t)MQ * NTYP;       // 524288
    unsigned short* Pg  = (unsigned short*)(ws + off); off += (size_t)MQ * NTYP / 2;
    float* bias = ws + off; off += 320;
    unsigned short* BT  = (unsigned short*)(ws + off); off += (320 * 512) / 2;
    unsigned short* WqB = (unsigned short*)(ws + off); off += (512 * 256) / 2;
    int* cnt        = (int*)(ws + off); off += GG;
    int* ofs        = (int*)(ws + off); off += GG;
    int* rank       = (int*)(ws + off); off += NMEM;
    int* tok_sorted = (int*)(ws + off); off += NMEM;
    int* ofs_n      = (int*)(ws + off); off += N_SEQ + 1;

    // init: Wq->bf16 + zero cnt + per-n ranges
    k_init<<<136, 256, 0, stream>>>(Wq, WqB, (int4*)cnt, idx, ofs_n);

    // hist || BT build (independent, one launch)
    k_histw<<<1044, 256, 0, stream>>>(grp, cnt, rank, Wk, bq, WqB, Wrel, brel,
                                      BT, bias);

    // scan (block 0) || gemm (blocks 1..512)
    k_sg<<<513, 256, 0, stream>>>(cnt, ofs, h_grp, idx, srcv, dstv, BT, bias,
                                  qkb, part);

    // permute || attention-score (independent: score needs qkb+h, not zw)
    k_pscore<<<2048, 256, 0, stream>>>(grp, mem, ofs, rank, tok_sorted,
                                       h_grp, ofs_n, msk, qkb, Pg);

    // zsum (round-17 proven body)
    k_zsum<<<GG, 128, 0, stream>>>(ofs, cnt, tok_sorted, tok_emb, Wrel, zw);

    // ctx MFMA + epilogue (P from global)
    k_ctx<<<N_SEQ, 256, 0, stream>>>(ofs_n, pos2grp, zw, Pg, part, out);
}

// Round 24
// 99.535 us; speedup vs baseline: 1.0493x; 1.0493x over previous
//
#include <hip/hip_runtime.h>
#include <math.h>

#define N_SEQ 1024
#define LL 64
#define DH 256
#define DX 128
#define MQ 8192
#define GG 4096
#define NTYP 64
#define NMEM 262144
#define N_TOK 10000

typedef __attribute__((ext_vector_type(8))) short short8v;
typedef __attribute__((ext_vector_type(4))) float float4v;

__device__ __forceinline__ unsigned short f2bf(float x) {
    unsigned int u = __float_as_uint(x);
    u += 0x7FFFu + ((u >> 16) & 1u);   // round-to-nearest-even
    return (unsigned short)(u >> 16);
}

__device__ __forceinline__ float bf2f(unsigned short u) {
    return __uint_as_float((unsigned int)u << 16);
}

// ---------------- init: Wq->bf16 (0..127), zero cnt (128..131),
//   per-n ranges (132..135), tok_emb->bf16 (136..1385) ----------------------
__global__ __launch_bounds__(256) void k_init(const float* __restrict__ Wq,
                                              unsigned short* __restrict__ WqB,
                                              int4* __restrict__ cnt4,
                                              const int* __restrict__ idx,
                                              int* __restrict__ ofs_n,
                                              const float* __restrict__ tok_emb,
                                              unsigned short* __restrict__ tok_bf) {
    int b = blockIdx.x, tid = threadIdx.x;
    if (b < 128) {
        int i = (b * 256 + tid) * 4;
        float4 v = *(const float4*)(Wq + i);
        ushort4 o;
        o.x = f2bf(v.x); o.y = f2bf(v.y); o.z = f2bf(v.z); o.w = f2bf(v.w);
        *(ushort4*)(WqB + i) = o;
    } else if (b < 132) {
        cnt4[(b - 128) * 256 + tid] = (int4){0, 0, 0, 0};
    } else if (b < 136) {
        int n = (b - 132) * 256 + tid;
        int lo = 0, hi = MQ;
        while (lo < hi) {
            int mid = (lo + hi) >> 1;
            if (idx[mid] < n) lo = mid + 1; else hi = mid;
        }
        ofs_n[n] = lo;
        if (n == 0) ofs_n[N_SEQ] = MQ;
    } else {
        int i = ((b - 136) * 256 + tid) * 4;   // 1250 blocks cover 1,280,000 elems
        float4 v = *(const float4*)(tok_emb + i);
        ushort4 o;
        o.x = f2bf(v.x); o.y = f2bf(v.y); o.z = f2bf(v.z); o.w = f2bf(v.w);
        *(ushort4*)(tok_bf + i) = o;
    }
}

// ---------------- hist (blocks 0..1023) || BT build (blocks 1024..1043) -----
__global__ __launch_bounds__(256) void k_histw(const int* __restrict__ grp,
                                               int* __restrict__ cnt,
                                               int* __restrict__ rank,
                                               const float* __restrict__ Wk,
                                               const float* __restrict__ bq,
                                               const unsigned short* __restrict__ WqB,
                                               const float* __restrict__ Wrel,
                                               const float* __restrict__ brel,
                                               unsigned short* __restrict__ BT,
                                               float* __restrict__ bias) {
    __shared__ __align__(16) unsigned short A[16 * 256];
    __shared__ float bred[16][17];
    int b = blockIdx.x, tid = threadIdx.x;
    if (b < 1024) {
        int i = b * 256 + tid;
        rank[i] = atomicAdd(&cnt[grp[i]], 1);
        return;
    }
    int b2 = b - 1024;
    if (b2 < 16) {
        int n0 = b2 * 16;
        {
            int r = tid >> 4;
            int kc = (tid & 15) * 16;
            const float4* s4 = (const float4*)(Wk + (size_t)(n0 + r) * 256 + kc);
            unsigned short* Arow = A + r * 256;
#pragma unroll
            for (int j = 0; j < 2; ++j) {
                float4 lo = s4[j * 2], hi = s4[j * 2 + 1];
                unsigned short tmp[8];
                tmp[0] = f2bf(lo.x); tmp[1] = f2bf(lo.y);
                tmp[2] = f2bf(lo.z); tmp[3] = f2bf(lo.w);
                tmp[4] = f2bf(hi.x); tmp[5] = f2bf(hi.y);
                tmp[6] = f2bf(hi.z); tmp[7] = f2bf(hi.w);
                int c = (kc >> 3) + j;
                int cs = (c & ~7) | ((c & 7) ^ (r & 7));
                *(int4*)(Arow + cs * 8) = *(int4*)tmp;
            }
        }
        __syncthreads();
        int w = tid >> 6, lane = tid & 63;
        int r = lane & 15, kq = lane >> 4;
        float4v acc[8];
#pragma unroll
        for (int t = 0; t < 8; ++t) acc[t] = (float4v){0.f, 0.f, 0.f, 0.f};
        const unsigned short* Arow = A + r * 256;
#pragma unroll
        for (int ks = 0; ks < 8; ++ks) {
            int c = ks * 4 + kq;
            int cs = (c & ~7) | ((c & 7) ^ (r & 7));
            short8v a = *(const short8v*)(Arow + cs * 8);
            int kk = ks * 32 + kq * 8;
#pragma unroll
            for (int t = 0; t < 8; ++t) {
                int jcol = w * 128 + t * 16 + r;
                short8v bf = *(const short8v*)(WqB + (size_t)jcol * 256 + kk);
                acc[t] = __builtin_amdgcn_mfma_f32_16x16x32_bf16(a, bf, acc[t], 0, 0, 0);
            }
        }
#pragma unroll
        for (int t = 0; t < 8; ++t) {
            int jcol = w * 128 + t * 16 + r;
#pragma unroll
            for (int j = 0; j < 4; ++j)
                BT[(size_t)(n0 + kq * 4 + j) * 512 + jcol] = f2bf(acc[t][j]);
        }
        {
            int n16 = tid >> 4, seg = tid & 15;
            const float* wkr = Wk + (size_t)(n0 + n16) * 256 + seg * 16;
            const float* bqr = bq + seg * 16;
            float pb = 0.f;
#pragma unroll
            for (int i = 0; i < 16; ++i) pb += wkr[i] * bqr[i];
            bred[n16][seg] = pb;
        }
        __syncthreads();
        if (tid < 16) {
            float s = 0.f;
#pragma unroll
            for (int k2 = 0; k2 < 16; ++k2) s += bred[tid][k2];
            bias[n0 + tid] = s;
        }
    } else {
        int t0 = (b2 - 16) * 16;
#pragma unroll
        for (int jj = 0; jj < 2; ++jj) {
            int j = tid + jj * 256;
            const float* wr = Wrel + (size_t)j * NTYP + t0;
#pragma unroll
            for (int tt = 0; tt < 16; ++tt)
                BT[(size_t)(256 + t0 + tt) * 512 + j] = f2bf(wr[tt]);
        }
        if (b2 == 16 && tid < 64) bias[256 + tid] = brel[tid];
    }
}

// ---------------- scan (block 0, 256 thr) || gemm (blocks 1..512) -----------
__global__ __launch_bounds__(256) void k_sg(const int* __restrict__ cnt,
                                            int* __restrict__ ofs,
                                            const float* __restrict__ h_grp,
                                            const int* __restrict__ idx,
                                            const int* __restrict__ srcv,
                                            const int* __restrict__ dstv,
                                            const unsigned short* __restrict__ BT,
                                            const float* __restrict__ bias,
                                            unsigned short* __restrict__ qkb,
                                            float* __restrict__ part) {
    __shared__ __align__(16) unsigned short A[16 * 512];
    __shared__ int ns[16], ss[16], dsv[16];
    int b = blockIdx.x, tid = threadIdx.x;
    if (b == 0) {
        int* wsum = (int*)A;
        int lane = tid & 63, w = tid >> 6;
        int c[16];
        int tsum = 0;
        int base0 = tid * 16;
#pragma unroll
        for (int j = 0; j < 16; ++j) { c[j] = cnt[base0 + j]; tsum += c[j]; }
        int v = tsum;
        for (int o2 = 1; o2 < 64; o2 <<= 1) {
            int t = __shfl_up(v, o2);
            if (lane >= o2) v += t;
        }
        if (lane == 63) wsum[w] = v;
        __syncthreads();
        int wb = 0;
#pragma unroll
        for (int q2 = 0; q2 < 4; ++q2) if (q2 < w) wb += wsum[q2];
        int base = wb + v - tsum;
#pragma unroll
        for (int j = 0; j < 16; ++j) { ofs[base0 + j] = base; base += c[j]; }
        return;
    }
    int bid = b - 1;
    int swz = (bid & 7) * 64 + (bid >> 3);   // 512 blocks, XCD-chunked
    int m0 = swz * 16;
    if (tid < 16) {
        int m = m0 + tid;
        ns[tid] = idx[m];
        ss[tid] = srcv[m];
        dsv[tid] = dstv[m];
    }
    __syncthreads();
    {
        int r = tid >> 4;
        int kc = (tid & 15) * 32;
        const float* src = h_grp +
            ((size_t)ns[r] * LL + (kc < 256 ? ss[r] : dsv[r])) * DH + (kc & 255);
        const float4* s4 = (const float4*)src;
        float4 f[8];
#pragma unroll
        for (int j = 0; j < 8; ++j) f[j] = s4[j];
        unsigned short* Arow = A + r * 512;
#pragma unroll
        for (int j = 0; j < 4; ++j) {
            int c = (kc >> 3) + j;
            int cs = (c & ~7) | ((c & 7) ^ (r & 7));
            unsigned short tmp[8];
            float4 lo = f[j * 2], hi = f[j * 2 + 1];
            tmp[0] = f2bf(lo.x); tmp[1] = f2bf(lo.y);
            tmp[2] = f2bf(lo.z); tmp[3] = f2bf(lo.w);
            tmp[4] = f2bf(hi.x); tmp[5] = f2bf(hi.y);
            tmp[6] = f2bf(hi.z); tmp[7] = f2bf(hi.w);
            *(int4*)(Arow + cs * 8) = *(int4*)tmp;
        }
    }
    __syncthreads();

    int w = tid >> 6, lane = tid & 63;
    int r = lane & 15;
    int q = lane >> 4;
    int n0 = w * 80;
    float4v acc[5];
#pragma unroll
    for (int t = 0; t < 5; ++t) {
        float b3 = bias[n0 + t * 16 + r];
        acc[t] = (float4v){b3, b3, b3, b3};
    }
    const unsigned short* Arow = A + r * 512;
#pragma unroll 2
    for (int ks = 0; ks < 16; ++ks) {
        int c = ks * 4 + q;
        int cs = (c & ~7) | ((c & 7) ^ (r & 7));
        short8v a = *(const short8v*)(Arow + cs * 8);
        int kk = ks * 32 + q * 8;
#pragma unroll
        for (int t = 0; t < 5; ++t) {
            int n = n0 + t * 16 + r;
            short8v b3 = *(const short8v*)(BT + (size_t)n * 512 + kk);
            acc[t] = __builtin_amdgcn_mfma_f32_16x16x32_bf16(a, b3, acc[t], 0, 0, 0);
        }
    }
#pragma unroll
    for (int t = 0; t < 5; ++t) {
        int n = n0 + t * 16 + r;
        if (n < 256) {
#pragma unroll
            for (int j = 0; j < 4; ++j)
                qkb[(size_t)(m0 + q * 4 + j) * 256 + n] = f2bf(acc[t][j]);
        } else {
#pragma unroll
            for (int j = 0; j < 4; ++j)
                part[(size_t)(m0 + q * 4 + j) * NTYP + (n - 256)] = acc[t][j];
        }
    }
}

__global__ __launch_bounds__(256) void k_permute(const int* __restrict__ grp,
                                                 const int* __restrict__ mem,
                                                 const int* __restrict__ ofs,
                                                 const int* __restrict__ rank,
                                                 int* __restrict__ tok_sorted) {
    int i = blockIdx.x * 256 + threadIdx.x;
    if (i < NMEM) tok_sorted[ofs[grp[i]] + rank[i]] = mem[i];
}

// z[g] = sum tok_bf rows (bf16 gather, fp32 accumulate, 4 tokens in parallel);
// fused: zw[g] = z[g] @ Wrel[512:640]
__global__ __launch_bounds__(128) void k_zsum(const int* __restrict__ ofs,
                                              const int* __restrict__ cnt,
                                              const int* __restrict__ tok_sorted,
                                              const unsigned short* __restrict__ tok_bf,
                                              const float* __restrict__ Wrel,
                                              float* __restrict__ zw) {
    __shared__ int idxs[128];
    __shared__ float red[4][128];
    __shared__ float zs[128];
    int g = blockIdx.x;
    int tid = threadIdx.x;
    int gq = tid >> 5;
    int s = tid & 31;
    int start = ofs[g], n = cnt[g];
    float4 a0 = {0.f, 0.f, 0.f, 0.f}, a1 = {0.f, 0.f, 0.f, 0.f};
    for (int j0 = 0; j0 < n; j0 += 128) {
        __syncthreads();
        int rem = n - j0;
        if (tid < rem) idxs[tid] = tok_sorted[start + j0 + tid];
        __syncthreads();
        int kmax = rem < 128 ? rem : 128;
        int k = gq;
        for (; k + 4 < kmax; k += 8) {
            ushort4 v0 = ((const ushort4*)(tok_bf + (size_t)idxs[k] * DX))[s];
            ushort4 v1 = ((const ushort4*)(tok_bf + (size_t)idxs[k + 4] * DX))[s];
            a0.x += bf2f(v0.x); a0.y += bf2f(v0.y);
            a0.z += bf2f(v0.z); a0.w += bf2f(v0.w);
            a1.x += bf2f(v1.x); a1.y += bf2f(v1.y);
            a1.z += bf2f(v1.z); a1.w += bf2f(v1.w);
        }
        if (k < kmax) {
            ushort4 v0 = ((const ushort4*)(tok_bf + (size_t)idxs[k] * DX))[s];
            a0.x += bf2f(v0.x); a0.y += bf2f(v0.y);
            a0.z += bf2f(v0.z); a0.w += bf2f(v0.w);
        }
    }
    a0.x += a1.x; a0.y += a1.y; a0.z += a1.z; a0.w += a1.w;
    ((float4*)red[gq])[s] = a0;
    __syncthreads();
    zs[tid] = red[0][tid] + red[1][tid] + red[2][tid] + red[3][tid];
    __syncthreads();
    if (tid < NTYP) {
        float a2s = 0.f;
#pragma unroll 8
        for (int v = 0; v < DX; ++v)
            a2s += zs[v] * Wrel[(size_t)(512 + v) * NTYP + tid];
        zw[(size_t)g * NTYP + tid] = a2s;
    }
}

// ---------------- attention: per-n, A-fragments direct from global ----------
__global__ __launch_bounds__(256) void k_attn9(const float* __restrict__ h_grp,
                                               const int* __restrict__ ofs_n,
                                               const int* __restrict__ pos2grp,
                                               const int* __restrict__ msk,
                                               const float* __restrict__ zw,
                                               const unsigned short* __restrict__ qkb,
                                               const float* __restrict__ part,
                                               float* __restrict__ out) {
    __shared__ __align__(16) unsigned short zwT[64][72];   // 9.2 KB
    __shared__ __align__(16) unsigned short PsT[16][72];   // 2.3 KB
    __shared__ float red0[4][16], red1[4][16];

    int bid = blockIdx.x;
    int n = (bid & 7) * 128 + (bid >> 3);      // XCD-chunked over 1024
    int start = ofs_n[n];
    int nq = ofs_n[n + 1] - start;
    if (nq <= 0) return;

    int tid = threadIdx.x;
    int w = tid >> 6, lane = tid & 63;
    int q15 = lane & 15, kq = lane >> 4;

    int mk = msk[n * LL + lane];
    int gv = pos2grp[n * LL + lane];

    // stage zwT[c][l] = bf16(zw[g_l][c])
    {
        int l = 16 * w + (lane >> 2);
        int cb = (lane & 3) * 16;
        int gl = __shfl(gv, l);
        const float4* zr4 = (const float4*)(zw + (size_t)gl * NTYP + cb);
#pragma unroll
        for (int i4 = 0; i4 < 4; ++i4) {
            float4 zv = zr4[i4];
            zwT[cb + i4 * 4 + 0][l] = f2bf(zv.x);
            zwT[cb + i4 * 4 + 1][l] = f2bf(zv.y);
            zwT[cb + i4 * 4 + 2][l] = f2bf(zv.z);
            zwT[cb + i4 * 4 + 3][l] = f2bf(zv.w);
        }
    }

    // A-fragments direct from global h (loop-invariant): row 16w+q15
    const float* hrow = h_grp + ((size_t)n * LL + 16 * w + q15) * DH;
    short8v afrag[8];
#pragma unroll
    for (int ks = 0; ks < 8; ++ks) {
        const float4* p = (const float4*)(hrow + ks * 32 + kq * 8);
        float4 f0 = p[0], f1 = p[1];
        unsigned short t[8];
        t[0] = f2bf(f0.x); t[1] = f2bf(f0.y);
        t[2] = f2bf(f0.z); t[3] = f2bf(f0.w);
        t[4] = f2bf(f1.x); t[5] = f2bf(f1.y);
        t[6] = f2bf(f1.z); t[7] = f2bf(f1.w);
        afrag[ks] = *(short8v*)t;
    }
    __syncthreads();

    for (int t0 = 0; t0 < nq; t0 += 16) {
        int nqt = nq - t0; if (nqt > 16) nqt = 16;
        if (t0 > 0) __syncthreads();   // protect PsT from prev-tile readers

        // ---- GEMM2: S[64 l][16 q] = H @ qkb^T (A regs, B direct from L2) ----
        int mq = start + t0 + (q15 < nqt ? q15 : 0);
        const unsigned short* qrow = qkb + (size_t)mq * 256;
        float4v sacc = (float4v){0.f, 0.f, 0.f, 0.f};
#pragma unroll
        for (int ks = 0; ks < 8; ++ks) {
            short8v b = *(const short8v*)(qrow + ks * 32 + kq * 8);
            sacc = __builtin_amdgcn_mfma_f32_16x16x32_bf16(afrag[ks], b, sacc, 0, 0, 0);
        }
        float sv[4];
#pragma unroll
        for (int j = 0; j < 4; ++j) {
            int l = 16 * w + kq * 4 + j;
            int mkl = __shfl(mk, l);
            sv[j] = mkl ? sacc[j] * 0.0625f : -INFINITY;
        }
        // ---- parallel softmax over l ----
        float pmax = fmaxf(fmaxf(sv[0], sv[1]), fmaxf(sv[2], sv[3]));
        pmax = fmaxf(pmax, __shfl_xor(pmax, 16));
        pmax = fmaxf(pmax, __shfl_xor(pmax, 32));
        if (lane < 16) red0[w][lane] = pmax;
        __syncthreads();
        float mx = fmaxf(fmaxf(red0[0][q15], red0[1][q15]),
                         fmaxf(red0[2][q15], red0[3][q15]));
        float pe[4];
        float psum = 0.f;
#pragma unroll
        for (int j = 0; j < 4; ++j) { pe[j] = __expf(sv[j] - mx); psum += pe[j]; }
        psum += __shfl_xor(psum, 16);
        psum += __shfl_xor(psum, 32);
        if (lane < 16) red1[w][lane] = psum;
        __syncthreads();
        float inv = 1.0f / (red1[0][q15] + red1[1][q15] + red1[2][q15] + red1[3][q15]);
        ushort4 pk;
        pk.x = f2bf(pe[0] * inv); pk.y = f2bf(pe[1] * inv);
        pk.z = f2bf(pe[2] * inv); pk.w = f2bf(pe[3] * inv);
        *(ushort4*)(&PsT[q15][16 * w + kq * 4]) = pk;
        __syncthreads();

        // ---- ctx MFMA: C[16 q][64] = PsT(16x64) @ zwT^T ----
        float4v cacc[4];
#pragma unroll
        for (int ct = 0; ct < 4; ++ct) cacc[ct] = (float4v){0.f, 0.f, 0.f, 0.f};
#pragma unroll
        for (int ks = 0; ks < 2; ++ks) {
            short8v a = *(const short8v*)(&PsT[q15][ks * 32 + kq * 8]);
#pragma unroll
            for (int ct = 0; ct < 4; ++ct) {
                short8v b = *(const short8v*)(&zwT[ct * 16 + q15][ks * 32 + kq * 8]);
                cacc[ct] = __builtin_amdgcn_mfma_f32_16x16x32_bf16(a, b, cacc[ct], 0, 0, 0);
            }
        }
        // ---- epilogue: out = part (brel folded) + ctx ----
#pragma unroll
        for (int ct = 0; ct < 4; ++ct) {
            int col = ct * 16 + q15;
#pragma unroll
            for (int j = 0; j < 4; ++j) {
                int qrow2 = kq * 4 + j;
                if (qrow2 < nqt) {
                    size_t m = (size_t)(start + t0 + qrow2);
                    out[m * NTYP + col] = part[m * NTYP + col] + cacc[ct][j];
                }
            }
        }
    }
}

extern "C" void kernel_launch(void* const* d_in, const int* in_sizes, int n_in,
                              void* d_out, int out_size, void* d_ws, size_t ws_size,
                              hipStream_t stream) {
    const int*   mem     = (const int*)d_in[0];
    const int*   grp     = (const int*)d_in[1];
    const int*   pos2grp = (const int*)d_in[2];
    const float* h_grp   = (const float*)d_in[3];
    const int*   msk     = (const int*)d_in[4];
    const int*   idx     = (const int*)d_in[5];
    const int*   srcv    = (const int*)d_in[6];
    const int*   dstv    = (const int*)d_in[7];
    // d_in[8] = typ (unused by the reference)
    const float* tok_emb = (const float*)d_in[9];
    const float* Wq      = (const float*)d_in[10];
    const float* bq      = (const float*)d_in[11];
    const float* Wk      = (const float*)d_in[12];
    const float* bk      = (const float*)d_in[13];  // softmax-invariant: unused
    const float* Wrel    = (const float*)d_in[14];
    const float* brel    = (const float*)d_in[15];
    float* out = (float*)d_out;
    (void)bk;

    float* ws = (float*)d_ws;
    size_t off = 0;
    float* zw   = ws + off; off += (size_t)GG * NTYP;       // 262144
    unsigned short* qkb = (unsigned short*)(ws + off); off += (size_t)MQ * 256 / 2;
    float* part = ws + off; off += (size_t)MQ * NTYP;       // 524288
    float* bias = ws + off; off += 320;
    unsigned short* BT  = (unsigned short*)(ws + off); off += (320 * 512) / 2;
    unsigned short* WqB = (unsigned short*)(ws + off); off += (512 * 256) / 2;
    unsigned short* tok_bf = (unsigned short*)(ws + off); off += (size_t)N_TOK * DX / 2;
    int* cnt        = (int*)(ws + off); off += GG;
    int* ofs        = (int*)(ws + off); off += GG;
    int* rank       = (int*)(ws + off); off += NMEM;
    int* tok_sorted = (int*)(ws + off); off += NMEM;
    int* ofs_n      = (int*)(ws + off); off += N_SEQ + 1;

    // init: Wq->bf16 + zero cnt + per-n ranges + tok_emb->bf16
    k_init<<<1386, 256, 0, stream>>>(Wq, WqB, (int4*)cnt, idx, ofs_n,
                                     tok_emb, tok_bf);

    // hist || BT build (independent, one launch)
    k_histw<<<1044, 256, 0, stream>>>(grp, cnt, rank, Wk, bq, WqB, Wrel, brel,
                                      BT, bias);

    // scan (block 0) || gemm (blocks 1..512)
    k_sg<<<513, 256, 0, stream>>>(cnt, ofs, h_grp, idx, srcv, dstv, BT, bias,
                                  qkb, part);

    k_permute<<<NMEM / 256, 256, 0, stream>>>(grp, mem, ofs, rank, tok_sorted);

    // zsum (bf16 gather, fp32 accumulate)
    k_zsum<<<GG, 128, 0, stream>>>(ofs, cnt, tok_sorted, tok_bf, Wrel, zw);

    // per-n MFMA attention
    k_attn9<<<N_SEQ, 256, 0, stream>>>(h_grp, ofs_n, pos2grp, msk, zw, qkb, part, out);
}

// Round 25
// 99.532 us; speedup vs baseline: 1.0493x; 1.0000x over previous
//
#include <hip/hip_runtime.h>
#include <math.h>

#define N_SEQ 1024
#define LL 64
#define DH 256
#define DX 128
#define MQ 8192
#define GG 4096
#define NTYP 64
#define NMEM 262144
#define N_TOK 10000

typedef __attribute__((ext_vector_type(8))) short short8v;
typedef __attribute__((ext_vector_type(4))) float float4v;

__device__ __forceinline__ unsigned short f2bf(float x) {
    unsigned int u = __float_as_uint(x);
    u += 0x7FFFu + ((u >> 16) & 1u);   // round-to-nearest-even
    return (unsigned short)(u >> 16);
}

__device__ __forceinline__ float bf2f(unsigned short u) {
    return __uint_as_float((unsigned int)u << 16);
}

// ---------------- init: Wq->bf16 (0..127), zero cnt (128..131),
//   per-n ranges (132..135), tok_emb->bf16 (136..1385) ----------------------
__global__ __launch_bounds__(256) void k_init(const float* __restrict__ Wq,
                                              unsigned short* __restrict__ WqB,
                                              int4* __restrict__ cnt4,
                                              const int* __restrict__ idx,
                                              int* __restrict__ ofs_n,
                                              const float* __restrict__ tok_emb,
                                              unsigned short* __restrict__ tok_bf) {
    int b = blockIdx.x, tid = threadIdx.x;
    if (b < 128) {
        int i = (b * 256 + tid) * 4;
        float4 v = *(const float4*)(Wq + i);
        ushort4 o;
        o.x = f2bf(v.x); o.y = f2bf(v.y); o.z = f2bf(v.z); o.w = f2bf(v.w);
        *(ushort4*)(WqB + i) = o;
    } else if (b < 132) {
        cnt4[(b - 128) * 256 + tid] = (int4){0, 0, 0, 0};
    } else if (b < 136) {
        int n = (b - 132) * 256 + tid;
        int lo = 0, hi = MQ;
        while (lo < hi) {
            int mid = (lo + hi) >> 1;
            if (idx[mid] < n) lo = mid + 1; else hi = mid;
        }
        ofs_n[n] = lo;
        if (n == 0) ofs_n[N_SEQ] = MQ;
    } else {
        int i = ((b - 136) * 256 + tid) * 4;   // 1250 blocks cover 1,280,000 elems
        float4 v = *(const float4*)(tok_emb + i);
        ushort4 o;
        o.x = f2bf(v.x); o.y = f2bf(v.y); o.z = f2bf(v.z); o.w = f2bf(v.w);
        *(ushort4*)(tok_bf + i) = o;
    }
}

// ---------------- hist (blocks 0..1023) || BT build (blocks 1024..1043) -----
__global__ __launch_bounds__(256) void k_histw(const int* __restrict__ grp,
                                               int* __restrict__ cnt,
                                               int* __restrict__ rank,
                                               const float* __restrict__ Wk,
                                               const float* __restrict__ bq,
                                               const unsigned short* __restrict__ WqB,
                                               const float* __restrict__ Wrel,
                                               const float* __restrict__ brel,
                                               unsigned short* __restrict__ BT,
                                               float* __restrict__ bias) {
    __shared__ __align__(16) unsigned short A[16 * 256];
    __shared__ float bred[16][17];
    int b = blockIdx.x, tid = threadIdx.x;
    if (b < 1024) {
        int i = b * 256 + tid;
        rank[i] = atomicAdd(&cnt[grp[i]], 1);
        return;
    }
    int b2 = b - 1024;
    if (b2 < 16) {
        int n0 = b2 * 16;
        {
            int r = tid >> 4;
            int kc = (tid & 15) * 16;
            const float4* s4 = (const float4*)(Wk + (size_t)(n0 + r) * 256 + kc);
            unsigned short* Arow = A + r * 256;
#pragma unroll
            for (int j = 0; j < 2; ++j) {
                float4 lo = s4[j * 2], hi = s4[j * 2 + 1];
                unsigned short tmp[8];
                tmp[0] = f2bf(lo.x); tmp[1] = f2bf(lo.y);
                tmp[2] = f2bf(lo.z); tmp[3] = f2bf(lo.w);
                tmp[4] = f2bf(hi.x); tmp[5] = f2bf(hi.y);
                tmp[6] = f2bf(hi.z); tmp[7] = f2bf(hi.w);
                int c = (kc >> 3) + j;
                int cs = (c & ~7) | ((c & 7) ^ (r & 7));
                *(int4*)(Arow + cs * 8) = *(int4*)tmp;
            }
        }
        __syncthreads();
        int w = tid >> 6, lane = tid & 63;
        int r = lane & 15, kq = lane >> 4;
        float4v acc[8];
#pragma unroll
        for (int t = 0; t < 8; ++t) acc[t] = (float4v){0.f, 0.f, 0.f, 0.f};
        const unsigned short* Arow = A + r * 256;
#pragma unroll
        for (int ks = 0; ks < 8; ++ks) {
            int c = ks * 4 + kq;
            int cs = (c & ~7) | ((c & 7) ^ (r & 7));
            short8v a = *(const short8v*)(Arow + cs * 8);
            int kk = ks * 32 + kq * 8;
#pragma unroll
            for (int t = 0; t < 8; ++t) {
                int jcol = w * 128 + t * 16 + r;
                short8v bf = *(const short8v*)(WqB + (size_t)jcol * 256 + kk);
                acc[t] = __builtin_amdgcn_mfma_f32_16x16x32_bf16(a, bf, acc[t], 0, 0, 0);
            }
        }
#pragma unroll
        for (int t = 0; t < 8; ++t) {
            int jcol = w * 128 + t * 16 + r;
#pragma unroll
            for (int j = 0; j < 4; ++j)
                BT[(size_t)(n0 + kq * 4 + j) * 512 + jcol] = f2bf(acc[t][j]);
        }
        {
            int n16 = tid >> 4, seg = tid & 15;
            const float* wkr = Wk + (size_t)(n0 + n16) * 256 + seg * 16;
            const float* bqr = bq + seg * 16;
            float pb = 0.f;
#pragma unroll
            for (int i = 0; i < 16; ++i) pb += wkr[i] * bqr[i];
            bred[n16][seg] = pb;
        }
        __syncthreads();
        if (tid < 16) {
            float s = 0.f;
#pragma unroll
            for (int k2 = 0; k2 < 16; ++k2) s += bred[tid][k2];
            bias[n0 + tid] = s;
        }
    } else {
        int t0 = (b2 - 16) * 16;
#pragma unroll
        for (int jj = 0; jj < 2; ++jj) {
            int j = tid + jj * 256;
            const float* wr = Wrel + (size_t)j * NTYP + t0;
#pragma unroll
            for (int tt = 0; tt < 16; ++tt)
                BT[(size_t)(256 + t0 + tt) * 512 + j] = f2bf(wr[tt]);
        }
        if (b2 == 16 && tid < 64) bias[256 + tid] = brel[tid];
    }
}

// ---------------- scan (block 0, 256 thr) || gemm (blocks 1..512) -----------
__global__ __launch_bounds__(256) void k_sg(const int* __restrict__ cnt,
                                            int* __restrict__ ofs,
                                            const float* __restrict__ h_grp,
                                            const int* __restrict__ idx,
                                            const int* __restrict__ srcv,
                                            const int* __restrict__ dstv,
                                            const unsigned short* __restrict__ BT,
                                            const float* __restrict__ bias,
                                            unsigned short* __restrict__ qkb,
                                            float* __restrict__ part) {
    __shared__ __align__(16) unsigned short A[16 * 512];
    __shared__ int ns[16], ss[16], dsv[16];
    int b = blockIdx.x, tid = threadIdx.x;
    if (b == 0) {
        int* wsum = (int*)A;
        int lane = tid & 63, w = tid >> 6;
        int c[16];
        int tsum = 0;
        int base0 = tid * 16;
#pragma unroll
        for (int j = 0; j < 16; ++j) { c[j] = cnt[base0 + j]; tsum += c[j]; }
        int v = tsum;
        for (int o2 = 1; o2 < 64; o2 <<= 1) {
            int t = __shfl_up(v, o2);
            if (lane >= o2) v += t;
        }
        if (lane == 63) wsum[w] = v;
        __syncthreads();
        int wb = 0;
#pragma unroll
        for (int q2 = 0; q2 < 4; ++q2) if (q2 < w) wb += wsum[q2];
        int base = wb + v - tsum;
#pragma unroll
        for (int j = 0; j < 16; ++j) { ofs[base0 + j] = base; base += c[j]; }
        return;
    }
    int bid = b - 1;
    int swz = (bid & 7) * 64 + (bid >> 3);   // 512 blocks, XCD-chunked
    int m0 = swz * 16;
    if (tid < 16) {
        int m = m0 + tid;
        ns[tid] = idx[m];
        ss[tid] = srcv[m];
        dsv[tid] = dstv[m];
    }
    __syncthreads();
    {
        int r = tid >> 4;
        int kc = (tid & 15) * 32;
        const float* src = h_grp +
            ((size_t)ns[r] * LL + (kc < 256 ? ss[r] : dsv[r])) * DH + (kc & 255);
        const float4* s4 = (const float4*)src;
        float4 f[8];
#pragma unroll
        for (int j = 0; j < 8; ++j) f[j] = s4[j];
        unsigned short* Arow = A + r * 512;
#pragma unroll
        for (int j = 0; j < 4; ++j) {
            int c = (kc >> 3) + j;
            int cs = (c & ~7) | ((c & 7) ^ (r & 7));
            unsigned short tmp[8];
            float4 lo = f[j * 2], hi = f[j * 2 + 1];
            tmp[0] = f2bf(lo.x); tmp[1] = f2bf(lo.y);
            tmp[2] = f2bf(lo.z); tmp[3] = f2bf(lo.w);
            tmp[4] = f2bf(hi.x); tmp[5] = f2bf(hi.y);
            tmp[6] = f2bf(hi.z); tmp[7] = f2bf(hi.w);
            *(int4*)(Arow + cs * 8) = *(int4*)tmp;
        }
    }
    __syncthreads();

    int w = tid >> 6, lane = tid & 63;
    int r = lane & 15;
    int q = lane >> 4;
    int n0 = w * 80;
    float4v acc[5];
#pragma unroll
    for (int t = 0; t < 5; ++t) {
        float b3 = bias[n0 + t * 16 + r];
        acc[t] = (float4v){b3, b3, b3, b3};
    }
    const unsigned short* Arow = A + r * 512;
#pragma unroll 2
    for (int ks = 0; ks < 16; ++ks) {
        int c = ks * 4 + q;
        int cs = (c & ~7) | ((c & 7) ^ (r & 7));
        short8v a = *(const short8v*)(Arow + cs * 8);
        int kk = ks * 32 + q * 8;
#pragma unroll
        for (int t = 0; t < 5; ++t) {
            int n = n0 + t * 16 + r;
            short8v b3 = *(const short8v*)(BT + (size_t)n * 512 + kk);
            acc[t] = __builtin_amdgcn_mfma_f32_16x16x32_bf16(a, b3, acc[t], 0, 0, 0);
        }
    }
#pragma unroll
    for (int t = 0; t < 5; ++t) {
        int n = n0 + t * 16 + r;
        if (n < 256) {
#pragma unroll
            for (int j = 0; j < 4; ++j)
                qkb[(size_t)(m0 + q * 4 + j) * 256 + n] = f2bf(acc[t][j]);
        } else {
#pragma unroll
            for (int j = 0; j < 4; ++j)
                part[(size_t)(m0 + q * 4 + j) * NTYP + (n - 256)] = acc[t][j];
        }
    }
}

__global__ __launch_bounds__(256) void k_permute(const int* __restrict__ grp,
                                                 const int* __restrict__ mem,
                                                 const int* __restrict__ ofs,
                                                 const int* __restrict__ rank,
                                                 int* __restrict__ tok_sorted) {
    int i = blockIdx.x * 256 + threadIdx.x;
    if (i < NMEM) tok_sorted[ofs[grp[i]] + rank[i]] = mem[i];
}

// z[g] = sum tok_bf rows (bf16 gather, fp32 accumulate, 4-deep ILP);
// fused: zw[g] = z[g] @ Wrel[512:640]
__global__ __launch_bounds__(128) void k_zsum(const int* __restrict__ ofs,
                                              const int* __restrict__ cnt,
                                              const int* __restrict__ tok_sorted,
                                              const unsigned short* __restrict__ tok_bf,
                                              const float* __restrict__ Wrel,
                                              float* __restrict__ zw) {
    __shared__ int idxs[128];
    __shared__ float red[4][128];
    __shared__ float zs[128];
    int g = blockIdx.x;
    int tid = threadIdx.x;
    int gq = tid >> 5;
    int s = tid & 31;
    int start = ofs[g], n = cnt[g];
    float4 a0 = {0.f, 0.f, 0.f, 0.f}, a1 = {0.f, 0.f, 0.f, 0.f};
    float4 a2 = {0.f, 0.f, 0.f, 0.f}, a3 = {0.f, 0.f, 0.f, 0.f};
    for (int j0 = 0; j0 < n; j0 += 128) {
        __syncthreads();
        int rem = n - j0;
        if (tid < rem) idxs[tid] = tok_sorted[start + j0 + tid];
        __syncthreads();
        int kmax = rem < 128 ? rem : 128;
        int k = gq;
        for (; k + 12 < kmax; k += 16) {
            ushort4 v0 = ((const ushort4*)(tok_bf + (size_t)idxs[k] * DX))[s];
            ushort4 v1 = ((const ushort4*)(tok_bf + (size_t)idxs[k + 4] * DX))[s];
            ushort4 v2 = ((const ushort4*)(tok_bf + (size_t)idxs[k + 8] * DX))[s];
            ushort4 v3 = ((const ushort4*)(tok_bf + (size_t)idxs[k + 12] * DX))[s];
            a0.x += bf2f(v0.x); a0.y += bf2f(v0.y);
            a0.z += bf2f(v0.z); a0.w += bf2f(v0.w);
            a1.x += bf2f(v1.x); a1.y += bf2f(v1.y);
            a1.z += bf2f(v1.z); a1.w += bf2f(v1.w);
            a2.x += bf2f(v2.x); a2.y += bf2f(v2.y);
            a2.z += bf2f(v2.z); a2.w += bf2f(v2.w);
            a3.x += bf2f(v3.x); a3.y += bf2f(v3.y);
            a3.z += bf2f(v3.z); a3.w += bf2f(v3.w);
        }
        for (; k < kmax; k += 4) {
            ushort4 v0 = ((const ushort4*)(tok_bf + (size_t)idxs[k] * DX))[s];
            a0.x += bf2f(v0.x); a0.y += bf2f(v0.y);
            a0.z += bf2f(v0.z); a0.w += bf2f(v0.w);
        }
    }
    a0.x += a1.x; a0.y += a1.y; a0.z += a1.z; a0.w += a1.w;
    a2.x += a3.x; a2.y += a3.y; a2.z += a3.z; a2.w += a3.w;
    a0.x += a2.x; a0.y += a2.y; a0.z += a2.z; a0.w += a2.w;
    ((float4*)red[gq])[s] = a0;
    __syncthreads();
    zs[tid] = red[0][tid] + red[1][tid] + red[2][tid] + red[3][tid];
    __syncthreads();
    if (tid < NTYP) {
        float a2s = 0.f;
#pragma unroll 8
        for (int v = 0; v < DX; ++v)
            a2s += zs[v] * Wrel[(size_t)(512 + v) * NTYP + tid];
        zw[(size_t)g * NTYP + tid] = a2s;
    }
}

// ---------------- attention: per-n, A-fragments direct from global ----------
__global__ __launch_bounds__(256) void k_attn9(const float* __restrict__ h_grp,
                                               const int* __restrict__ ofs_n,
                                               const int* __restrict__ pos2grp,
                                               const int* __restrict__ msk,
                                               const float* __restrict__ zw,
                                               const unsigned short* __restrict__ qkb,
                                               const float* __restrict__ part,
                                               float* __restrict__ out) {
    __shared__ __align__(16) unsigned short zwT[64][72];   // 9.2 KB
    __shared__ __align__(16) unsigned short PsT[16][72];   // 2.3 KB
    __shared__ float red0[4][16], red1[4][16];

    int bid = blockIdx.x;
    int n = (bid & 7) * 128 + (bid >> 3);      // XCD-chunked over 1024
    int start = ofs_n[n];
    int nq = ofs_n[n + 1] - start;
    if (nq <= 0) return;

    int tid = threadIdx.x;
    int w = tid >> 6, lane = tid & 63;
    int q15 = lane & 15, kq = lane >> 4;

    int mk = msk[n * LL + lane];
    int gv = pos2grp[n * LL + lane];

    // stage zwT[c][l] = bf16(zw[g_l][c])
    {
        int l = 16 * w + (lane >> 2);
        int cb = (lane & 3) * 16;
        int gl = __shfl(gv, l);
        const float4* zr4 = (const float4*)(zw + (size_t)gl * NTYP + cb);
#pragma unroll
        for (int i4 = 0; i4 < 4; ++i4) {
            float4 zv = zr4[i4];
            zwT[cb + i4 * 4 + 0][l] = f2bf(zv.x);
            zwT[cb + i4 * 4 + 1][l] = f2bf(zv.y);
            zwT[cb + i4 * 4 + 2][l] = f2bf(zv.z);
            zwT[cb + i4 * 4 + 3][l] = f2bf(zv.w);
        }
    }

    // A-fragments direct from global h (loop-invariant): row 16w+q15
    const float* hrow = h_grp + ((size_t)n * LL + 16 * w + q15) * DH;
    short8v afrag[8];
#pragma unroll
    for (int ks = 0; ks < 8; ++ks) {
        const float4* p = (const float4*)(hrow + ks * 32 + kq * 8);
        float4 f0 = p[0], f1 = p[1];
        unsigned short t[8];
        t[0] = f2bf(f0.x); t[1] = f2bf(f0.y);
        t[2] = f2bf(f0.z); t[3] = f2bf(f0.w);
        t[4] = f2bf(f1.x); t[5] = f2bf(f1.y);
        t[6] = f2bf(f1.z); t[7] = f2bf(f1.w);
        afrag[ks] = *(short8v*)t;
    }
    __syncthreads();

    for (int t0 = 0; t0 < nq; t0 += 16) {
        int nqt = nq - t0; if (nqt > 16) nqt = 16;
        if (t0 > 0) __syncthreads();   // protect PsT from prev-tile readers

        // ---- GEMM2: S[64 l][16 q] = H @ qkb^T (A regs, B direct from L2) ----
        int mq = start + t0 + (q15 < nqt ? q15 : 0);
        const unsigned short* qrow = qkb + (size_t)mq * 256;
        float4v sacc = (float4v){0.f, 0.f, 0.f, 0.f};
#pragma unroll
        for (int ks = 0; ks < 8; ++ks) {
            short8v b = *(const short8v*)(qrow + ks * 32 + kq * 8);
            sacc = __builtin_amdgcn_mfma_f32_16x16x32_bf16(afrag[ks], b, sacc, 0, 0, 0);
        }
        float sv[4];
#pragma unroll
        for (int j = 0; j < 4; ++j) {
            int l = 16 * w + kq * 4 + j;
            int mkl = __shfl(mk, l);
            sv[j] = mkl ? sacc[j] * 0.0625f : -INFINITY;
        }
        // ---- parallel softmax over l ----
        float pmax = fmaxf(fmaxf(sv[0], sv[1]), fmaxf(sv[2], sv[3]));
        pmax = fmaxf(pmax, __shfl_xor(pmax, 16));
        pmax = fmaxf(pmax, __shfl_xor(pmax, 32));
        if (lane < 16) red0[w][lane] = pmax;
        __syncthreads();
        float mx = fmaxf(fmaxf(red0[0][q15], red0[1][q15]),
                         fmaxf(red0[2][q15], red0[3][q15]));
        float pe[4];
        float psum = 0.f;
#pragma unroll
        for (int j = 0; j < 4; ++j) { pe[j] = __expf(sv[j] - mx); psum += pe[j]; }
        psum += __shfl_xor(psum, 16);
        psum += __shfl_xor(psum, 32);
        if (lane < 16) red1[w][lane] = psum;
        __syncthreads();
        float inv = 1.0f / (red1[0][q15] + red1[1][q15] + red1[2][q15] + red1[3][q15]);
        ushort4 pk;
        pk.x = f2bf(pe[0] * inv); pk.y = f2bf(pe[1] * inv);
        pk.z = f2bf(pe[2] * inv); pk.w = f2bf(pe[3] * inv);
        *(ushort4*)(&PsT[q15][16 * w + kq * 4]) = pk;
        __syncthreads();

        // ---- ctx MFMA: C[16 q][64] = PsT(16x64) @ zwT^T ----
        float4v cacc[4];
#pragma unroll
        for (int ct = 0; ct < 4; ++ct) cacc[ct] = (float4v){0.f, 0.f, 0.f, 0.f};
#pragma unroll
        for (int ks = 0; ks < 2; ++ks) {
            short8v a = *(const short8v*)(&PsT[q15][ks * 32 + kq * 8]);
#pragma unroll
            for (int ct = 0; ct < 4; ++ct) {
                short8v b = *(const short8v*)(&zwT[ct * 16 + q15][ks * 32 + kq * 8]);
                cacc[ct] = __builtin_amdgcn_mfma_f32_16x16x32_bf16(a, b, cacc[ct], 0, 0, 0);
            }
        }
        // ---- epilogue: out = part (brel folded) + ctx ----
#pragma unroll
        for (int ct = 0; ct < 4; ++ct) {
            int col = ct * 16 + q15;
#pragma unroll
            for (int j = 0; j < 4; ++j) {
                int qrow2 = kq * 4 + j;
                if (qrow2 < nqt) {
                    size_t m = (size_t)(start + t0 + qrow2);
                    out[m * NTYP + col] = part[m * NTYP + col] + cacc[ct][j];
                }
            }
        }
    }
}

extern "C" void kernel_launch(void* const* d_in, const int* in_sizes, int n_in,
                              void* d_out, int out_size, void* d_ws, size_t ws_size,
                              hipStream_t stream) {
    const int*   mem     = (const int*)d_in[0];
    const int*   grp     = (const int*)d_in[1];
    const int*   pos2grp = (const int*)d_in[2];
    const float* h_grp   = (const float*)d_in[3];
    const int*   msk     = (const int*)d_in[4];
    const int*   idx     = (const int*)d_in[5];
    const int*   srcv    = (const int*)d_in[6];
    const int*   dstv    = (const int*)d_in[7];
    // d_in[8] = typ (unused by the reference)
    const float* tok_emb = (const float*)d_in[9];
    const float* Wq      = (const float*)d_in[10];
    const float* bq      = (const float*)d_in[11];
    const float* Wk      = (const float*)d_in[12];
    const float* bk      = (const float*)d_in[13];  // softmax-invariant: unused
    const float* Wrel    = (const float*)d_in[14];
    const float* brel    = (const float*)d_in[15];
    float* out = (float*)d_out;
    (void)bk;

    float* ws = (float*)d_ws;
    size_t off = 0;
    float* zw   = ws + off; off += (size_t)GG * NTYP;       // 262144
    unsigned short* qkb = (unsigned short*)(ws + off); off += (size_t)MQ * 256 / 2;
    float* part = ws + off; off += (size_t)MQ * NTYP;       // 524288
    float* bias = ws + off; off += 320;
    unsigned short* BT  = (unsigned short*)(ws + off); off += (320 * 512) / 2;
    unsigned short* WqB = (unsigned short*)(ws + off); off += (512 * 256) / 2;
    unsigned short* tok_bf = (unsigned short*)(ws + off); off += (size_t)N_TOK * DX / 2;
    int* cnt        = (int*)(ws + off); off += GG;
    int* ofs        = (int*)(ws + off); off += GG;
    int* rank       = (int*)(ws + off); off += NMEM;
    int* tok_sorted = (int*)(ws + off); off += NMEM;
    int* ofs_n      = (int*)(ws + off); off += N_SEQ + 1;

    // init: Wq->bf16 + zero cnt + per-n ranges + tok_emb->bf16
    k_init<<<1386, 256, 0, stream>>>(Wq, WqB, (int4*)cnt, idx, ofs_n,
                                     tok_emb, tok_bf);

    // hist || BT build (independent, one launch)
    k_histw<<<1044, 256, 0, stream>>>(grp, cnt, rank, Wk, bq, WqB, Wrel, brel,
                                      BT, bias);

    // scan (block 0) || gemm (blocks 1..512)
    k_sg<<<513, 256, 0, stream>>>(cnt, ofs, h_grp, idx, srcv, dstv, BT, bias,
                                  qkb, part);

    k_permute<<<NMEM / 256, 256, 0, stream>>>(grp, mem, ofs, rank, tok_sorted);

    // zsum (bf16 gather, fp32 accumulate, 4-deep ILP)
    k_zsum<<<GG, 128, 0, stream>>>(ofs, cnt, tok_sorted, tok_bf, Wrel, zw);

    // per-n MFMA attention
    k_attn9<<<N_SEQ, 256, 0, stream>>>(h_grp, ofs_n, pos2grp, msk, zw, qkb, part, out);
}